// Round 5
// baseline (398.184 us; speedup 1.0000x reference)
//
#include <hip/hip_runtime.h>
#include <hip/hip_bf16.h>

#define NN 100000
#define FF 256
#define DD 128
#define EE 1000000
#define NPX (NN / 8)          // 12500 nodes per XCD slice
#define CH 8192               // edges per chunk (per relation)
#define NCH 123               // ceil(EE / CH)

typedef __attribute__((ext_vector_type(4))) float f32x4;
typedef __attribute__((ext_vector_type(8))) short bf16x8;

__device__ __forceinline__ ushort f2bf(float f) {
    __hip_bfloat16 h = __float2bfloat16(f);
    return *reinterpret_cast<ushort*>(&h);
}
__device__ __forceinline__ float bf2f(ushort u) {
    return __uint_as_float(((uint)u) << 16);
}

// ---------------- pack W_lin (fp32 [256][128]) -> Wt (bf16 [128][256]) ----------------
__global__ void pack_w(const float* __restrict__ Wl, ushort* __restrict__ Wt) {
    int id = blockIdx.x * 256 + threadIdx.x;  // 32768 total
    int k = id >> 7, n = id & 127;
    Wt[n * FF + k] = f2bf(Wl[id]);
}

// ---------------- fused: h = x@W+b (bf16 MFMA), beta = softmax(x@Wc^T+bc) ----------------
__global__ __launch_bounds__(256) void fused_h(const float* __restrict__ x,
                                               const ushort* __restrict__ Wt,
                                               const float* __restrict__ bl,
                                               const float* __restrict__ Wc,
                                               const float* __restrict__ bc,
                                               ushort* __restrict__ hb,
                                               float* __restrict__ beta) {
    __shared__ ushort xs[64][72];    // 64 rows x BK=64 bf16, pad 8
    __shared__ ushort wsT[128][72];  // 128 cols x BK=64 bf16 (W transposed), pad 8
    __shared__ ushort hs[64][136];   // epilogue staging: 64 rows x 128, pad 8
    __shared__ float wcs[768];       // W_conv 3x256

    int t = threadIdx.x;
    int wv = t >> 6, lane = t & 63;
    int row0 = blockIdx.x * 64;
    int br = t >> 2, bq = t & 3;     // staging/beta: row br, k-quarter bq
    bool rowok = (row0 + br) < NN;

    if (t < 192) ((float4*)wcs)[t] = ((const float4*)Wc)[t];
    __syncthreads();

    f32x4 acc[8];
    #pragma unroll
    for (int i = 0; i < 8; ++i) acc[i] = (f32x4){0.f, 0.f, 0.f, 0.f};

    float bs0 = 0.f, bs1 = 0.f, bs2 = 0.f;

    for (int k0 = 0; k0 < FF; k0 += 64) {
        if (rowok) {
            const float4* xp = (const float4*)(x + (size_t)(row0 + br) * FF + k0 + bq * 16);
            #pragma unroll
            for (int j = 0; j < 4; ++j) {
                float4 v = xp[j];
                int kk = bq * 16 + j * 4;
                const float* w0 = wcs + k0 + kk;
                bs0 += v.x * w0[0] + v.y * w0[1] + v.z * w0[2] + v.w * w0[3];
                const float* w1 = wcs + 256 + k0 + kk;
                bs1 += v.x * w1[0] + v.y * w1[1] + v.z * w1[2] + v.w * w1[3];
                const float* w2 = wcs + 512 + k0 + kk;
                bs2 += v.x * w2[0] + v.y * w2[1] + v.z * w2[2] + v.w * w2[3];
                ushort4 p;
                p.x = f2bf(v.x); p.y = f2bf(v.y); p.z = f2bf(v.z); p.w = f2bf(v.w);
                *(ushort4*)&xs[br][kk] = p;
            }
        } else {
            ushort4 z = {0, 0, 0, 0};
            #pragma unroll
            for (int j = 0; j < 4; ++j) *(ushort4*)&xs[br][bq * 16 + j * 4] = z;
        }
        #pragma unroll
        for (int j = 0; j < 4; ++j) {
            int c = t + 256 * j;
            int rw = c >> 3, seg = c & 7;   // 128 rows x 8 segs
            uint4 v = *(const uint4*)(Wt + rw * FF + k0 + seg * 8);
            *(uint4*)&wsT[rw][seg * 8] = v;
        }
        __syncthreads();
        #pragma unroll
        for (int ks = 0; ks < 2; ++ks) {
            bf16x8 af = *(const bf16x8*)&xs[wv * 16 + (lane & 15)][ks * 32 + (lane >> 4) * 8];
            #pragma unroll
            for (int nt = 0; nt < 8; ++nt) {
                bf16x8 bv = *(const bf16x8*)&wsT[nt * 16 + (lane & 15)][ks * 32 + (lane >> 4) * 8];
                acc[nt] = __builtin_amdgcn_mfma_f32_16x16x32_bf16(af, bv, acc[nt], 0, 0, 0);
            }
        }
        __syncthreads();
    }

    bs0 += __shfl_xor(bs0, 1); bs0 += __shfl_xor(bs0, 2);
    bs1 += __shfl_xor(bs1, 1); bs1 += __shfl_xor(bs1, 2);
    bs2 += __shfl_xor(bs2, 1); bs2 += __shfl_xor(bs2, 2);
    if (bq == 0 && rowok) {
        float s0 = bs0 + bc[0], s1 = bs1 + bc[1], s2 = bs2 + bc[2];
        float mx = fmaxf(s0, fmaxf(s1, s2));
        float e0 = __expf(s0 - mx), e1 = __expf(s1 - mx), e2 = __expf(s2 - mx);
        float inv = 1.f / (e0 + e1 + e2);
        int n = row0 + br;
        beta[n * 3 + 0] = e0 * inv;
        beta[n * 3 + 1] = e1 * inv;
        beta[n * 3 + 2] = e2 * inv;
    }

    #pragma unroll
    for (int nt = 0; nt < 8; ++nt) {
        int col = nt * 16 + (lane & 15);
        float bias = bl[col];
        int rbase = wv * 16 + (lane >> 4) * 4;
        #pragma unroll
        for (int r = 0; r < 4; ++r) {
            hs[rbase + r][col] = f2bf(acc[nt][r] + bias);
        }
    }
    __syncthreads();
    #pragma unroll
    for (int j = 0; j < 4; ++j) {
        int c = t + 256 * j;
        int rw = c >> 4, seg = c & 15;   // 64 rows x 16 segs
        if (row0 + rw < NN) {
            uint4 v = *(const uint4*)&hs[rw][seg * 8];
            *(uint4*)(hb + (size_t)(row0 + rw) * DD + seg * 8) = v;
        }
    }
}

// ---------------- al/ar attention dots per node (bf16 h) ----------------
__global__ __launch_bounds__(256) void alr_kernel(const ushort* __restrict__ hb,
                                                  const float* __restrict__ attn_l,
                                                  const float* __restrict__ attn_r,
                                                  float* __restrict__ AL,
                                                  float* __restrict__ AR) {
    int wid = threadIdx.x >> 6, lane = threadIdx.x & 63;
    int n = blockIdx.x * 4 + wid;
    uint hv = ((const uint*)hb)[(size_t)n * 64 + lane];
    float hx = bf2f((ushort)(hv & 0xffff)), hy = bf2f((ushort)(hv >> 16));
    int hd = lane >> 4;
    int cg = lane & 15;
    #pragma unroll
    for (int m = 0; m < 2; ++m) {
        float2 wl = ((const float2*)attn_l)[m * 64 + hd * 16 + cg];
        float2 wr = ((const float2*)attn_r)[m * 64 + hd * 16 + cg];
        float sl = hx * wl.x + hy * wl.y;
        float sr = hx * wr.x + hy * wr.y;
        for (int off = 1; off < 16; off <<= 1) {
            sl += __shfl_xor(sl, off);
            sr += __shfl_xor(sr, off);
        }
        if (cg == 0) {
            AL[(size_t)(m * NN + n) * 4 + hd] = sl;
            AR[(size_t)(m * NN + n) * 4 + hd] = sr;
        }
    }
}

// ---------------- CSR build: XCD-partitioned, int4-vectorized ----------------
// blockIdx&7 = XCD slice (round-robin dispatch); b>>3 enumerates (relation, chunk).
// Each block scans one relation-chunk with int4 loads, filters dsts to its slice.
__global__ __launch_bounds__(256) void count_kernel(const int* __restrict__ ei0,
                                                    const int* __restrict__ ei1,
                                                    int* __restrict__ deg) {
    int b = blockIdx.x;
    int lo = (b & 7) * NPX, hi = lo + NPX;
    int q = b >> 3;
    int rel = q / NCH, ch = q - rel * NCH;
    const int* dstrow = rel ? ei1 : ei0;
    int base = rel * NN;
    int e0 = ch * CH;
    for (int i = threadIdx.x; i < CH / 4; i += 256) {
        int e = e0 + i * 4;
        if (e + 4 <= EE) {
            int4 d = *(const int4*)(dstrow + e);
            if (d.x >= lo && d.x < hi) atomicAdd(&deg[base + d.x], 1);
            if (d.y >= lo && d.y < hi) atomicAdd(&deg[base + d.y], 1);
            if (d.z >= lo && d.z < hi) atomicAdd(&deg[base + d.z], 1);
            if (d.w >= lo && d.w < hi) atomicAdd(&deg[base + d.w], 1);
        }
    }
}

__global__ __launch_bounds__(256) void scatter_kernel(const int* __restrict__ ei0,
                                                      const int* __restrict__ ei1,
                                                      const int* __restrict__ rp,
                                                      int* __restrict__ cursor,
                                                      int* __restrict__ srcs) {
    int b = blockIdx.x;
    int lo = (b & 7) * NPX, hi = lo + NPX;
    int q = b >> 3;
    int rel = q / NCH, ch = q - rel * NCH;
    const int* row = rel ? ei1 : ei0;
    int base = rel * NN;
    int e0 = ch * CH;
    for (int i = threadIdx.x; i < CH / 4; i += 256) {
        int e = e0 + i * 4;
        if (e + 4 <= EE) {
            int4 d = *(const int4*)(row + e);
            int4 s = *(const int4*)(row + EE + e);
            if (d.x >= lo && d.x < hi) { int idx = base + d.x; srcs[rp[idx] + atomicAdd(&cursor[idx], 1)] = s.x; }
            if (d.y >= lo && d.y < hi) { int idx = base + d.y; srcs[rp[idx] + atomicAdd(&cursor[idx], 1)] = s.y; }
            if (d.z >= lo && d.z < hi) { int idx = base + d.z; srcs[rp[idx] + atomicAdd(&cursor[idx], 1)] = s.z; }
            if (d.w >= lo && d.w < hi) { int idx = base + d.w; srcs[rp[idx] + atomicAdd(&cursor[idx], 1)] = s.w; }
        }
    }
}

// ---------------- scans ----------------
__global__ __launch_bounds__(256) void scan1(const int* __restrict__ deg, int* __restrict__ rp,
                                             int* __restrict__ bsum, int L) {
    __shared__ int sm[256];
    int t = threadIdx.x;
    int i = blockIdx.x * 256 + t;
    int v = (i < L) ? deg[i] : 0;
    sm[t] = v;
    __syncthreads();
    for (int off = 1; off < 256; off <<= 1) {
        int o = (t >= off) ? sm[t - off] : 0;
        __syncthreads();
        sm[t] += o;
        __syncthreads();
    }
    if (i < L) rp[i] = sm[t] - v;
    if (t == 255) bsum[blockIdx.x] = sm[255];
}

__global__ __launch_bounds__(256) void scan2(int* __restrict__ bsum, int nb) {
    __shared__ int sm[256];
    int t = threadIdx.x;
    int carry = 0;
    for (int base = 0; base < nb; base += 256) {
        int i = base + t;
        int v = (i < nb) ? bsum[i] : 0;
        __syncthreads();
        sm[t] = v;
        __syncthreads();
        for (int off = 1; off < 256; off <<= 1) {
            int o = (t >= off) ? sm[t - off] : 0;
            __syncthreads();
            sm[t] += o;
            __syncthreads();
        }
        int incl = sm[t];
        int tot = sm[255];
        if (i < nb) bsum[i] = carry + incl - v;
        carry += tot;
    }
}

__global__ void scan3(int* __restrict__ rp, const int* __restrict__ bsum, int L) {
    int i = blockIdx.x * 256 + threadIdx.x;
    if (i < L) rp[i] += bsum[blockIdx.x];
    if (i == 0) rp[L] = 2 * EE;
}

// ---------------- main v2: wave per (dst, relation); halves process alternate
// edges, 4 channels/lane via uint2 gather; 32-bit saddr offsets ----------------
__global__ __launch_bounds__(256) void main_kernel(const ushort* __restrict__ hb,
                                                   const float* __restrict__ AL,
                                                   const float* __restrict__ AR,
                                                   const float* __restrict__ beta,
                                                   const float* __restrict__ alpha_act,
                                                   const int* __restrict__ rp,
                                                   const int* __restrict__ srcs,
                                                   float* __restrict__ out) {
    __shared__ float4 contribs[2][32];   // relation-1 contribution per dst slot
    int w = threadIdx.x >> 6, lane = threadIdx.x & 63;
    int slot = w >> 1, m = w & 1;
    int n = blockIdx.x * 2 + slot;
    int half = lane >> 5, sl = lane & 31;
    int hd = sl >> 3;                     // head = channel-quad / 8
    const char* h8 = (const char*)hb;     // byte base for 32-bit voffset addressing
    const char* ar8 = (const char*)(AR + (size_t)m * NN * 4);
    const char* sr8 = (const char*)srcs;
    uint aoff = (uint)(hd << 2);
    uint hoff = (uint)(sl << 3);

    float alv = AL[(size_t)(m * NN + n) * 4 + hd];
    float am = alpha_act[m];
    int e0 = rp[m * NN + n];
    int e1 = rp[m * NN + n + 1];

    float denom = 0.f, a0 = 0.f, a1 = 0.f, a2 = 0.f, a3 = 0.f;
    for (int k = e0 + half; k < e1; k += 2) {
        int s = *(const int*)(sr8 + ((uint)k << 2));
        float r = *(const float*)(ar8 + ((uint)s * 16u + aoff));
        uint2 g = *(const uint2*)(h8 + ((uint)s * 256u + hoff));
        float p = __expf((r + alv) * am);
        denom += p;
        a0 = fmaf(p, __uint_as_float(g.x << 16), a0);
        a1 = fmaf(p, __uint_as_float(g.x & 0xffff0000u), a1);
        a2 = fmaf(p, __uint_as_float(g.y << 16), a2);
        a3 = fmaf(p, __uint_as_float(g.y & 0xffff0000u), a3);
    }
    // combine the two edge-halves
    denom += __shfl_xor(denom, 32);
    a0 += __shfl_xor(a0, 32);
    a1 += __shfl_xor(a1, 32);
    a2 += __shfl_xor(a2, 32);
    a3 += __shfl_xor(a3, 32);
    float invd = (denom > 0.f) ? (1.f / denom) : 0.f;
    float bm = beta[n * 3 + m] * invd;
    float4 c;
    c.x = a0 * bm; c.y = a1 * bm; c.z = a2 * bm; c.w = a3 * bm;

    if (m == 1 && half == 0) contribs[slot][sl] = c;
    __syncthreads();
    if (m == 0 && half == 0) {
        uint2 hv = *(const uint2*)(h8 + ((uint)n * 256u + hoff));
        float b2 = beta[n * 3 + 2];
        float4 c1 = contribs[slot][sl];
        float4 res;
        res.x = fmaxf(fmaf(b2, __uint_as_float(hv.x << 16), c.x + c1.x), 0.f);
        res.y = fmaxf(fmaf(b2, __uint_as_float(hv.x & 0xffff0000u), c.y + c1.y), 0.f);
        res.z = fmaxf(fmaf(b2, __uint_as_float(hv.y << 16), c.z + c1.z), 0.f);
        res.w = fmaxf(fmaf(b2, __uint_as_float(hv.y & 0xffff0000u), c.w + c1.w), 0.f);
        *(float4*)(out + (size_t)n * 128 + sl * 4) = res;
    }
}

// ---------------- launch ----------------
extern "C" void kernel_launch(void* const* d_in, const int* in_sizes, int n_in,
                              void* d_out, int out_size, void* d_ws, size_t ws_size,
                              hipStream_t stream) {
    const float* x      = (const float*)d_in[0];
    const int*   ei0    = (const int*)d_in[1];
    const int*   ei1    = (const int*)d_in[2];
    const float* W_lin  = (const float*)d_in[3];
    const float* b_lin  = (const float*)d_in[4];
    const float* attn_l = (const float*)d_in[5];
    const float* attn_r = (const float*)d_in[6];
    const float* alpha  = (const float*)d_in[7];
    const float* W_conv = (const float*)d_in[8];
    const float* b_conv = (const float*)d_in[9];
    float* out = (float*)d_out;

    char* ws = (char*)d_ws;
    size_t off = 0;
    ushort* hb   = (ushort*)(ws + off); off += (size_t)NN * DD * 2;        // 25.6 MB
    ushort* Wt   = (ushort*)(ws + off); off += (size_t)DD * FF * 2;        // 64 KB
    float* AL    = (float*)(ws + off);  off += (size_t)2 * NN * 4 * 4;     // 3.2 MB
    float* AR    = (float*)(ws + off);  off += (size_t)2 * NN * 4 * 4;     // 3.2 MB
    float* beta  = (float*)(ws + off);  off += (size_t)NN * 3 * 4;         // 1.2 MB
    int*   deg   = (int*)(ws + off);    off += (size_t)2 * NN * 4;
    int*   cursor= (int*)(ws + off);    off += (size_t)2 * NN * 4;
    int*   rp    = (int*)(ws + off);    off += ((size_t)2 * NN + 4) * 4;
    int*   bsum  = (int*)(ws + off);    off += 1024 * 4;
    int*   srcs  = (int*)(ws + off);    off += (size_t)2 * EE * 4;         // 8 MB

    hipMemsetAsync(deg, 0, (size_t)4 * NN * 4, stream);

    pack_w<<<DD * FF / 256, 256, 0, stream>>>(W_lin, Wt);
    fused_h<<<(NN + 63) / 64, 256, 0, stream>>>(x, Wt, b_lin, W_conv, b_conv, hb, beta);
    alr_kernel<<<NN / 4, 256, 0, stream>>>(hb, attn_l, attn_r, AL, AR);
    count_kernel<<<2 * 8 * NCH, 256, 0, stream>>>(ei0, ei1, deg);
    int L = 2 * NN;
    int nb = (L + 255) / 256;
    scan1<<<nb, 256, 0, stream>>>(deg, rp, bsum, L);
    scan2<<<1, 256, 0, stream>>>(bsum, nb);
    scan3<<<nb, 256, 0, stream>>>(rp, bsum, L);
    scatter_kernel<<<2 * 8 * NCH, 256, 0, stream>>>(ei0, ei1, rp, cursor, srcs);
    main_kernel<<<NN / 2, 256, 0, stream>>>(hb, AL, AR, beta, alpha, rp, srcs, out);
}